// Round 3
// baseline (540.518 us; speedup 1.0000x reference)
//
#include <hip/hip_runtime.h>
#include <math.h>

#define N_ROWS 65536
#define Q 4096
#define E 64
#define BM 128            // rows per block
#define BQ 128            // codes per tile iteration
#define NTILE (Q / BQ)    // 32
#define LDP 68            // padded LDS row stride in floats (272B, 16B-aligned)

// Replicates numpy pairwise_sum of v[i]*v[i] for n=64 (validated absmax=0):
// r[0..7]=p[0..7]; stripes of 8; final ((r0+r1)+(r2+r3))+((r4+r5)+(r6+r7)).
__device__ __forceinline__ float pairwise_sq_sum64(const float* v) {
#pragma clang fp contract(off)
  float r[8];
#pragma unroll
  for (int j = 0; j < 8; ++j) r[j] = v[j] * v[j];
#pragma unroll
  for (int i = 8; i < 64; i += 8) {
#pragma unroll
    for (int j = 0; j < 8; ++j) {
      float p = v[i + j] * v[i + j];
      r[j] = r[j] + p;
    }
  }
  return ((r[0] + r[1]) + (r[2] + r[3])) + ((r[4] + r[5]) + (r[6] + r[7]));
}

__device__ __forceinline__ void load_row64(const float* __restrict__ src,
                                           float* dst) {
  const float4* p = (const float4*)src;
#pragma unroll
  for (int k4 = 0; k4 < 16; ++k4) {
    const float4 t = p[k4];
    dst[4 * k4 + 0] = t.x;
    dst[4 * k4 + 1] = t.y;
    dst[4 * k4 + 2] = t.z;
    dst[4 * k4 + 3] = t.w;
  }
}

// wsq[q] = numpy-pairwise sum(w[q]^2)
__global__ __launch_bounds__(256) void wsq_kernel(const float* __restrict__ w,
                                                  float* __restrict__ wsq) {
  const int q = blockIdx.x * 256 + threadIdx.x;
  float v[E];
  load_row64(w + (size_t)q * E, v);
  wsq[q] = pairwise_sq_sum64(v);
}

// hsq[n] = numpy-pairwise sum(x[n]^2)
__global__ __launch_bounds__(256) void hsq_kernel(const float* __restrict__ x,
                                                  float* __restrict__ hsq) {
  const int n = blockIdx.x * 256 + threadIdx.x;
  float v[E];
  load_row64(x + (size_t)n * E, v);
  hsq[n] = pairwise_sq_sum64(v);
}

// Register-tiled distance+argmin+gather. One block = 128 rows, loops all 32
// code tiles. Each thread: 8 rows x 8 codes accumulators. Dot = sequential
// fmaf k ascending (bit-identical to validated round-1/2 chain).
__global__ __launch_bounds__(256, 2) void dist_kernel(
    const float* __restrict__ x, const float* __restrict__ w,
    const float* __restrict__ wsq, const float* __restrict__ hsq,
    float* __restrict__ out) {
  __shared__ float As[BM * LDP];   // 34816 B
  __shared__ float Bs[BQ * LDP];   // 34816 B

  const int tid = threadIdx.x;
  const int tx = tid & 15;         // code group
  const int ty = tid >> 4;         // row group
  const int rowBase = blockIdx.x * BM;

  // ---- stage A-tile (once) ----
  {
    const int r = tid >> 1, h = tid & 1;  // 2 threads/row, 32 floats each
    const float4* src = (const float4*)(x + (size_t)(rowBase + r) * E + h * 32);
#pragma unroll
    for (int i = 0; i < 8; ++i) {
      const float4 t = src[i];
      *(float4*)&As[r * LDP + h * 32 + i * 4] = t;
    }
  }

  float hsqv[8];
#pragma unroll
  for (int r = 0; r < 8; ++r) hsqv[r] = hsq[rowBase + ty + 16 * r];

  float dmin[8];
  int best[8];
#pragma unroll
  for (int r = 0; r < 8; ++r) {
    dmin[r] = INFINITY;
    best[r] = 0;
  }

#pragma unroll 1
  for (int tile = 0; tile < NTILE; ++tile) {
    const int codeBase = tile * BQ;
    __syncthreads();  // previous iter's Bs readers done
    // ---- stage B-tile ----
    {
      const int r = tid >> 1, h = tid & 1;
      const float4* src =
          (const float4*)(w + (size_t)(codeBase + r) * E + h * 32);
#pragma unroll
      for (int i = 0; i < 8; ++i) {
        const float4 t = src[i];
        *(float4*)&Bs[r * LDP + h * 32 + i * 4] = t;
      }
    }
    __syncthreads();

    float acc[8][8];
#pragma unroll
    for (int r = 0; r < 8; ++r)
#pragma unroll
      for (int c = 0; c < 8; ++c) acc[r][c] = 0.f;

#pragma unroll
    for (int k4 = 0; k4 < 16; ++k4) {
      float a[8][4], b[8][4];
#pragma unroll
      for (int r = 0; r < 8; ++r) {
        const float4 t = *(const float4*)&As[(ty + 16 * r) * LDP + k4 * 4];
        a[r][0] = t.x; a[r][1] = t.y; a[r][2] = t.z; a[r][3] = t.w;
      }
#pragma unroll
      for (int c = 0; c < 8; ++c) {
        const float4 t = *(const float4*)&Bs[(tx + 16 * c) * LDP + k4 * 4];
        b[c][0] = t.x; b[c][1] = t.y; b[c][2] = t.z; b[c][3] = t.w;
      }
#pragma unroll
      for (int kk = 0; kk < 4; ++kk)
#pragma unroll
        for (int r = 0; r < 8; ++r)
#pragma unroll
          for (int c = 0; c < 8; ++c)
            acc[r][c] = fmaf(a[r][kk], b[c][kk], acc[r][c]);
    }

    // ---- epilogue: running argmin, codes ascend globally (strict < =
    // numpy first-occurrence within this thread's code subset) ----
    float wsqv[8];
#pragma unroll
    for (int c = 0; c < 8; ++c) wsqv[c] = wsq[codeBase + tx + 16 * c];
#pragma unroll
    for (int r = 0; r < 8; ++r) {
#pragma unroll
      for (int c = 0; c < 8; ++c) {
        // dist = RN( RN(hsq+wsq) - 2*dot ), 2*dot exact, fmaf rounds once
        const float d = fmaf(-2.f, acc[r][c], hsqv[r] + wsqv[c]);
        if (d < dmin[r]) {
          dmin[r] = d;
          best[r] = codeBase + tx + 16 * c;
        }
      }
    }
  }

  // ---- cross-tx reduction (reuse LDS), tie-break to lowest global index ----
  float* redD = Bs;                       // [BM][16]
  int* redI = (int*)(Bs + BM * 16);       // [BM][16]
  int* bestRow = (int*)As;                // [BM]
  __syncthreads();
#pragma unroll
  for (int r = 0; r < 8; ++r) {
    redD[(ty + 16 * r) * 16 + tx] = dmin[r];
    redI[(ty + 16 * r) * 16 + tx] = best[r];
  }
  __syncthreads();
  if (tid < BM) {
    float bd = INFINITY;
    int bi = 0;
#pragma unroll
    for (int t = 0; t < 16; ++t) {
      const float d = redD[tid * 16 + t];
      const int i = redI[tid * 16 + t];
      if (d < bd || (d == bd && i < bi)) {
        bd = d;
        bi = i;
      }
    }
    bestRow[tid] = bi;
    out[(size_t)N_ROWS * E + rowBase + tid] = (float)bi;
  }
  __syncthreads();
  // ---- gather codeword ----
  {
    const int r = tid >> 1, h = tid & 1;
    const int bi = bestRow[r];
    const float4* src = (const float4*)(w + (size_t)bi * E + h * 32);
    float4* dst = (float4*)(out + (size_t)(rowBase + r) * E + h * 32);
#pragma unroll
    for (int i = 0; i < 8; ++i) dst[i] = src[i];
  }
}

extern "C" void kernel_launch(void* const* d_in, const int* in_sizes, int n_in,
                              void* d_out, int out_size, void* d_ws,
                              size_t ws_size, hipStream_t stream) {
  const float* x = (const float*)d_in[0];
  const float* w = (const float*)d_in[1];
  float* out = (float*)d_out;

  // workspace: wsq[Q] | hsq[N_ROWS]   (272 KB)
  float* wsq = (float*)d_ws;
  float* hsq = wsq + Q;

  wsq_kernel<<<Q / 256, 256, 0, stream>>>(w, wsq);
  hsq_kernel<<<N_ROWS / 256, 256, 0, stream>>>(x, hsq);
  dist_kernel<<<N_ROWS / BM, 256, 0, stream>>>(x, w, wsq, hsq, out);
}

// Round 4
// 299.206 us; speedup vs baseline: 1.8065x; 1.8065x over previous
//
#include <hip/hip_runtime.h>
#include <math.h>

#define N_ROWS 65536
#define Q 4096
#define E 64
#define CT 64                 // codes staged per tile-step
#define NTS (Q / CT)          // 64 tile-steps
#define MARGIN 0.25f
#define CAP_LIST 8

typedef short s8v __attribute__((ext_vector_type(8)));   // 8 bf16 (4 VGPRs)
typedef float f4v __attribute__((ext_vector_type(4)));   // 4 fp32 acc

// ---------- exact-arithmetic helpers (validated absmax=0 rounds 1-3) ----------
__device__ __forceinline__ float pairwise_sq_sum64(const float* v) {
#pragma clang fp contract(off)
  float r[8];
#pragma unroll
  for (int j = 0; j < 8; ++j) r[j] = v[j] * v[j];
#pragma unroll
  for (int i = 8; i < 64; i += 8) {
#pragma unroll
    for (int j = 0; j < 8; ++j) {
      float p = v[i + j] * v[i + j];
      r[j] = r[j] + p;
    }
  }
  return ((r[0] + r[1]) + (r[2] + r[3])) + ((r[4] + r[5]) + (r[6] + r[7]));
}

__device__ __forceinline__ void load_row64(const float* __restrict__ src,
                                           float* dst) {
  const float4* p = (const float4*)src;
#pragma unroll
  for (int k4 = 0; k4 < 16; ++k4) {
    const float4 t = p[k4];
    dst[4 * k4 + 0] = t.x;
    dst[4 * k4 + 1] = t.y;
    dst[4 * k4 + 2] = t.z;
    dst[4 * k4 + 3] = t.w;
  }
}

// exact distance, reference-bitwise: sequential fmaf dot, RN(hsq+wsq), fmaf(-2,...)
__device__ __forceinline__ float exact_dist(const float* hv, float hs,
                                            const float* __restrict__ w,
                                            float wsqc, int c) {
  const float* wr = w + (size_t)c * E;
  float dot = 0.f;
#pragma unroll
  for (int k = 0; k < E; ++k) dot = fmaf(wr[k], hv[k], dot);
  return fmaf(-2.f, dot, hs + wsqc);
}

__device__ __forceinline__ unsigned short bf16_rn(float f) {
  unsigned int u = __float_as_uint(f);
  u += 0x7FFFu + ((u >> 16) & 1u);
  return (unsigned short)(u >> 16);
}
__device__ __forceinline__ float bf16_to_f(unsigned short s) {
  return __uint_as_float(((unsigned int)s) << 16);
}

// ---------- prep: wsq + bf16 hi/lo of w in staged (frag-order) layout ----------
// staged layout: [tile T=q>>6][unit = chunk*64 + (q&63)] of 8 bf16 (16B units)
__global__ __launch_bounds__(256) void prep_w(const float* __restrict__ w,
                                              float* __restrict__ wsq,
                                              short* __restrict__ whiS,
                                              short* __restrict__ wloS,
                                              int* __restrict__ ovfCnt) {
  const int q = blockIdx.x * 256 + threadIdx.x;
  if (q == 0) *ovfCnt = 0;
  float v[E];
  load_row64(w + (size_t)q * E, v);
  wsq[q] = pairwise_sq_sum64(v);
  const int T = q >> 6, code_in = q & 63;
#pragma unroll
  for (int ch = 0; ch < 8; ++ch) {
    s8v hi, lo;
#pragma unroll
    for (int j = 0; j < 8; ++j) {
      const float f = v[ch * 8 + j];
      const unsigned short h = bf16_rn(f);
      const float resid = f - bf16_to_f(h);
      hi[j] = (short)h;
      lo[j] = (short)bf16_rn(resid);
    }
    const size_t base = (size_t)T * 4096 + ((size_t)(ch * 64 + code_in)) * 8;
    *(s8v*)&whiS[base] = hi;
    *(s8v*)&wloS[base] = lo;
  }
}

__global__ __launch_bounds__(256) void prep_x(const float* __restrict__ x,
                                              float* __restrict__ hsq) {
  const int n = blockIdx.x * 256 + threadIdx.x;
  float v[E];
  load_row64(x + (size_t)n * E, v);
  hsq[n] = pairwise_sq_sum64(v);
}

// ---------- main: MFMA screen + per-lane top-3 + exact recheck + gather ------
// block = 256 thr = 4 waves; wave handles 32 rows (2 row-tiles of 16);
// block = 128 rows; grid = 512 (2 blocks/CU).
__global__ __launch_bounds__(256, 2) void dist_kernel(
    const float* __restrict__ x, const short* __restrict__ whiS,
    const short* __restrict__ wloS, const float* __restrict__ wsq,
    const float* __restrict__ hsq, const float* __restrict__ w,
    float* __restrict__ out, int* __restrict__ ovfCnt,
    int* __restrict__ ovfRows) {
  __shared__ short BsHi[CT * 64];    // 8 KB
  __shared__ short BsLo[CT * 64];    // 8 KB
  __shared__ float WsS[CT];
  __shared__ int cnt[128];
  __shared__ int flagS[128];
  __shared__ int lists[128][CAP_LIST];
  __shared__ int bestRow[128];

  const int tid = threadIdx.x;
  const int wv = tid >> 6;
  const int lane = tid & 63;
  const int n = lane & 15;
  const int quad = lane >> 4;
  const int rowBase = blockIdx.x * 128;

  if (tid < 128) {
    cnt[tid] = 0;
    flagS[tid] = 0;
  }

  // ---- A-frags: a = -2x, split hi/lo, built once (rows fixed per wave) ----
  // A[m=lane&15][k=quad*8+j], kstep ks covers k in [ks*32, ks*32+32)
  s8v ahi[2][2], alo[2][2];  // [rowtile][ks]
#pragma unroll
  for (int rt = 0; rt < 2; ++rt) {
#pragma unroll
    for (int ks = 0; ks < 2; ++ks) {
      const int gRow = rowBase + wv * 32 + rt * 16 + n;
      const float* xp = x + (size_t)gRow * E + ks * 32 + quad * 8;
      const float4 v0 = ((const float4*)xp)[0];
      const float4 v1 = ((const float4*)xp)[1];
      float vals[8] = {v0.x, v0.y, v0.z, v0.w, v1.x, v1.y, v1.z, v1.w};
      s8v hi, lo;
#pragma unroll
      for (int j = 0; j < 8; ++j) {
        const float a = -2.f * vals[j];
        const unsigned short h = bf16_rn(a);
        hi[j] = (short)h;
        lo[j] = (short)bf16_rn(a - bf16_to_f(h));
      }
      ahi[rt][ks] = hi;
      alo[rt][ks] = lo;
    }
  }

  // hsq for C-init rows (C/D layout: row = quad*4 + r)
  float hsqv[2][4];
#pragma unroll
  for (int rt = 0; rt < 2; ++rt)
#pragma unroll
    for (int r = 0; r < 4; ++r)
      hsqv[rt][r] = hsq[rowBase + wv * 32 + rt * 16 + quad * 4 + r];

  // per-lane top-3 (d, code) per row-slot; codes ascend -> strict < keeps first
  float m[2][4][3];
  int ci[2][4][3];
#pragma unroll
  for (int rt = 0; rt < 2; ++rt)
#pragma unroll
    for (int r = 0; r < 4; ++r)
#pragma unroll
      for (int k = 0; k < 3; ++k) {
        m[rt][r][k] = INFINITY;
        ci[rt][r][k] = 0;
      }

#pragma unroll 1
  for (int ts = 0; ts < NTS; ++ts) {
    __syncthreads();
    // stage 64 codes of w hi/lo (identity copy, frag-order) + wsq tile
    {
      const int4* gh = (const int4*)(whiS + (size_t)ts * 4096);
      const int4* gl = (const int4*)(wloS + (size_t)ts * 4096);
      ((int4*)BsHi)[tid] = gh[tid];
      ((int4*)BsHi)[tid + 256] = gh[tid + 256];
      ((int4*)BsLo)[tid] = gl[tid];
      ((int4*)BsLo)[tid + 256] = gl[tid + 256];
      if (tid < CT) WsS[tid] = wsq[ts * CT + tid];
    }
    __syncthreads();

#pragma unroll
    for (int ct = 0; ct < 4; ++ct) {
      // B-frags from LDS: unit = (ks*4+quad)*64 + ct*16 + n
      const s8v bhi0 = *(const s8v*)&BsHi[(size_t)((0 * 4 + quad) * 64 + ct * 16 + n) * 8];
      const s8v bhi1 = *(const s8v*)&BsHi[(size_t)((1 * 4 + quad) * 64 + ct * 16 + n) * 8];
      const s8v blo0 = *(const s8v*)&BsLo[(size_t)((0 * 4 + quad) * 64 + ct * 16 + n) * 8];
      const s8v blo1 = *(const s8v*)&BsLo[(size_t)((1 * 4 + quad) * 64 + ct * 16 + n) * 8];
      const float wsn = WsS[ct * 16 + n];
      const int codeT = ts * CT + ct * 16 + n;
#pragma unroll
      for (int rt = 0; rt < 2; ++rt) {
        f4v acc;
        acc[0] = hsqv[rt][0] + wsn;
        acc[1] = hsqv[rt][1] + wsn;
        acc[2] = hsqv[rt][2] + wsn;
        acc[3] = hsqv[rt][3] + wsn;
        acc = __builtin_amdgcn_mfma_f32_16x16x32_bf16(alo[rt][0], bhi0, acc, 0, 0, 0);
        acc = __builtin_amdgcn_mfma_f32_16x16x32_bf16(ahi[rt][0], blo0, acc, 0, 0, 0);
        acc = __builtin_amdgcn_mfma_f32_16x16x32_bf16(ahi[rt][0], bhi0, acc, 0, 0, 0);
        acc = __builtin_amdgcn_mfma_f32_16x16x32_bf16(alo[rt][1], bhi1, acc, 0, 0, 0);
        acc = __builtin_amdgcn_mfma_f32_16x16x32_bf16(ahi[rt][1], blo1, acc, 0, 0, 0);
        acc = __builtin_amdgcn_mfma_f32_16x16x32_bf16(ahi[rt][1], bhi1, acc, 0, 0, 0);
#pragma unroll
        for (int r = 0; r < 4; ++r) {
          const float d = acc[r];
          if (d < m[rt][r][2]) {
            if (d < m[rt][r][0]) {
              m[rt][r][2] = m[rt][r][1]; ci[rt][r][2] = ci[rt][r][1];
              m[rt][r][1] = m[rt][r][0]; ci[rt][r][1] = ci[rt][r][0];
              m[rt][r][0] = d;           ci[rt][r][0] = codeT;
            } else if (d < m[rt][r][1]) {
              m[rt][r][2] = m[rt][r][1]; ci[rt][r][2] = ci[rt][r][1];
              m[rt][r][1] = d;           ci[rt][r][1] = codeT;
            } else {
              m[rt][r][2] = d;           ci[rt][r][2] = codeT;
            }
          }
        }
      }
    }
  }

  // ---- candidate collection: rowmin via quad-local butterfly, push <= margin ----
  __syncthreads();
#pragma unroll
  for (int rt = 0; rt < 2; ++rt) {
#pragma unroll
    for (int r = 0; r < 4; ++r) {
      float rm = m[rt][r][0];
#pragma unroll
      for (int off = 1; off < 16; off <<= 1)
        rm = fminf(rm, __shfl_xor(rm, off, 64));
      const float thr = rm + MARGIN;
      const int row_l = wv * 32 + rt * 16 + quad * 4 + r;
#pragma unroll
      for (int k = 0; k < 3; ++k) {
        if (m[rt][r][k] <= thr) {
          const int pos = atomicAdd(&cnt[row_l], 1);
          if (pos < CAP_LIST) lists[row_l][pos] = ci[rt][r][k];
          else flagS[row_l] = 1;
        }
      }
      if (m[rt][r][2] <= thr) flagS[row_l] = 1;  // may have discarded in-margin
    }
  }
  __syncthreads();

  // ---- exact recheck (reference-bitwise) over candidates ----
  if (tid < 128) {
    const int g = rowBase + tid;
    if (flagS[tid]) {
      const int pos = atomicAdd(ovfCnt, 1);
      ovfRows[pos] = g;
    } else {
      float hv[E];
      load_row64(x + (size_t)g * E, hv);
      const float hs = hsq[g];
      const int nc = cnt[tid] < CAP_LIST ? cnt[tid] : CAP_LIST;
      float bd = INFINITY;
      int bi = 0x7FFFFFFF;
      for (int i = 0; i < nc; ++i) {
        const int c = lists[tid][i];
        const float d = exact_dist(hv, hs, w, wsq[c], c);
        if (d < bd || (d == bd && c < bi)) { bd = d; bi = c; }
      }
      bestRow[tid] = bi;
      out[(size_t)N_ROWS * E + g] = (float)bi;
    }
  }
  __syncthreads();
  // ---- gather codeword (2 threads/row x 32 floats) ----
  {
    const int r = tid >> 1, h = tid & 1;
    if (!flagS[r]) {
      const int bi = bestRow[r];
      const float4* src = (const float4*)(w + (size_t)bi * E + h * 32);
      float4* dst = (float4*)(out + (size_t)(rowBase + r) * E + h * 32);
#pragma unroll
      for (int i = 0; i < 8; ++i) dst[i] = src[i];
    }
  }
}

// ---------- fallback: full exact scan, one wave per overflow row ----------
__global__ __launch_bounds__(64) void fallback_kernel(
    const float* __restrict__ x, const float* __restrict__ w,
    const float* __restrict__ wsq, const float* __restrict__ hsq,
    float* __restrict__ out, const int* __restrict__ ovfCnt,
    const int* __restrict__ ovfRows) {
  const int novf = *ovfCnt;
  const int lane = threadIdx.x;
  for (int i = blockIdx.x; i < novf; i += gridDim.x) {
    const int row = ovfRows[i];
    float hv[E];
    load_row64(x + (size_t)row * E, hv);
    const float hs = hsq[row];
    float bd = INFINITY;
    int bi = 0x7FFFFFFF;
    for (int c0 = 0; c0 < 64; ++c0) {
      const int c = c0 * 64 + lane;
      const float d = exact_dist(hv, hs, w, wsq[c], c);
      if (d < bd || (d == bd && c < bi)) { bd = d; bi = c; }
    }
#pragma unroll
    for (int off = 1; off < 64; off <<= 1) {
      const float od = __shfl_xor(bd, off, 64);
      const int oi = __shfl_xor(bi, off, 64);
      if (od < bd || (od == bd && oi < bi)) { bd = od; bi = oi; }
    }
    if (lane == 0) out[(size_t)N_ROWS * E + row] = (float)bi;
    out[(size_t)row * E + lane] = w[(size_t)bi * E + lane];
  }
}

extern "C" void kernel_launch(void* const* d_in, const int* in_sizes, int n_in,
                              void* d_out, int out_size, void* d_ws,
                              size_t ws_size, hipStream_t stream) {
  const float* x = (const float*)d_in[0];
  const float* w = (const float*)d_in[1];
  float* out = (float*)d_out;

  // ws: wsq[4096] f32 | hsq[65536] f32 | whiS[262144] s16 | wloS[262144] s16
  //   | ovfCnt i32 | pad | ovfRows[65536] i32   (~1.6 MB)
  float* wsq = (float*)d_ws;
  float* hsq = wsq + Q;
  short* whiS = (short*)(hsq + N_ROWS);
  short* wloS = whiS + (size_t)Q * E;
  int* ovfCnt = (int*)(wloS + (size_t)Q * E);
  int* ovfRows = ovfCnt + 4;

  prep_w<<<Q / 256, 256, 0, stream>>>(w, wsq, whiS, wloS, ovfCnt);
  prep_x<<<N_ROWS / 256, 256, 0, stream>>>(x, hsq);
  dist_kernel<<<N_ROWS / 128, 256, 0, stream>>>(x, whiS, wloS, wsq, hsq, w, out,
                                                ovfCnt, ovfRows);
  fallback_kernel<<<256, 64, 0, stream>>>(x, w, wsq, hsq, out, ovfCnt, ovfRows);
}